// Round 1
// baseline (1197.342 us; speedup 1.0000x reference)
//
#include <hip/hip_runtime.h>
#include <math.h>

// Problem constants
#define BQ   4
#define GQ   8
#define NHQ  8
#define SQ   4096
#define SKQ  4100   // k/v row stride: cols 0..4095 = t, col 4096 = pad(t=S) column

// Workspace layout (floats):
//   qog : BQ*GQ*256*SQ  = 33,554,432   (q, later overwritten in-place by og)
//   kb  : BQ*GQ*256*SKQ = 33,587,200
//   vb  : BQ*GQ*256*SKQ = 33,587,200
// total = 402,915,328 bytes (~384 MiB) required in d_ws.

// ---------------------------------------------------------------------------
// Tiled fp32 GEMM: C[o][t] = sum_c A[g][o][c] * Bsrc[bg][c][t] + bias[g][o]
// Tile 128x128, BK=16, 256 threads, 8x8 micro-tile per thread.
// QKV=true: M=768, rows split j=o%3 -> (q, k, v) buffers.
// QKV=false: M=256, direct store to out0 (pred).
// ---------------------------------------------------------------------------
template <int M, bool QKV>
__global__ __launch_bounds__(256) void gemm_k(
    const float* __restrict__ A, const float* __restrict__ Bsrc,
    const float* __restrict__ bias,
    float* __restrict__ out0, float* __restrict__ out1, float* __restrict__ out2)
{
    const int bg = blockIdx.z;
    const int g  = bg & (GQ - 1);
    const int t0 = blockIdx.x << 7;
    const int o0 = blockIdx.y << 7;
    const float* Aw = A + (size_t)g * M * 256;
    const float* Bx = Bsrc + (size_t)bg * 256 * SQ;

    __shared__ float As[16][132];   // transposed A tile, padded rows
    __shared__ float Bs[16][128];

    const int tid = threadIdx.x;
    const int tx = tid & 15, ty = tid >> 4;

    float acc[8][8];
#pragma unroll
    for (int i = 0; i < 8; ++i)
#pragma unroll
        for (int j = 0; j < 8; ++j) acc[i][j] = 0.f;

    for (int k0 = 0; k0 < 256; k0 += 16) {
        // stage A: 128 o-rows x 16 k (transposed into As[k][o])
#pragma unroll
        for (int i = 0; i < 2; ++i) {
            int f = tid + (i << 8);           // 0..511
            int o = f >> 2, kq = f & 3;
            const float4 a4 = *(const float4*)(Aw + (size_t)(o0 + o) * 256 + k0 + (kq << 2));
            As[(kq << 2) + 0][o] = a4.x;
            As[(kq << 2) + 1][o] = a4.y;
            As[(kq << 2) + 2][o] = a4.z;
            As[(kq << 2) + 3][o] = a4.w;
        }
        // stage B: 16 k-rows x 128 t (coalesced)
#pragma unroll
        for (int i = 0; i < 2; ++i) {
            int f = tid + (i << 8);
            int r = f >> 5, tq = f & 31;
            const float4 b4 = *(const float4*)(Bx + (size_t)(k0 + r) * SQ + t0 + (tq << 2));
            *(float4*)&Bs[r][tq << 2] = b4;
        }
        __syncthreads();
#pragma unroll
        for (int kk = 0; kk < 16; ++kk) {
            const float4 a0 = *(const float4*)&As[kk][ty << 2];
            const float4 a1 = *(const float4*)&As[kk][64 + (ty << 2)];
            const float4 b0 = *(const float4*)&Bs[kk][tx << 2];
            const float4 b1 = *(const float4*)&Bs[kk][64 + (tx << 2)];
            const float av[8] = {a0.x, a0.y, a0.z, a0.w, a1.x, a1.y, a1.z, a1.w};
            const float bv[8] = {b0.x, b0.y, b0.z, b0.w, b1.x, b1.y, b1.z, b1.w};
#pragma unroll
            for (int i = 0; i < 8; ++i)
#pragma unroll
                for (int j = 0; j < 8; ++j)
                    acc[i][j] += av[i] * bv[j];
        }
        __syncthreads();
    }

    // epilogue: bias + stores (t-contiguous float4, coalesced)
#pragma unroll
    for (int oi = 0; oi < 8; ++oi) {
        const int o = o0 + ((oi < 4) ? (ty << 2) + oi : 64 + (ty << 2) + oi - 4);
        const float bo = bias[g * M + o];
        float* base;
        if (QKV) {
            const int j = o % 3, c = o / 3;
            if (j == 0)      base = out0 + ((size_t)(bg * 256 + c)) * SQ;
            else if (j == 1) base = out1 + ((size_t)(bg * 256 + c)) * SKQ;
            else             base = out2 + ((size_t)(bg * 256 + c)) * SKQ;
        } else {
            base = out0 + ((size_t)(bg * 256 + o)) * SQ;
        }
#pragma unroll
        for (int h = 0; h < 2; ++h) {
            const int t = t0 + (h << 6) + (tx << 2);
            float4 wv;
            wv.x = acc[oi][(h << 2) + 0] + bo;
            wv.y = acc[oi][(h << 2) + 1] + bo;
            wv.z = acc[oi][(h << 2) + 2] + bo;
            wv.w = acc[oi][(h << 2) + 3] + bo;
            *(float4*)(base + t) = wv;
        }
    }
}

// ---------------------------------------------------------------------------
// Pad column t=S of k/v: x pad column is zero -> value = bias only.
// ---------------------------------------------------------------------------
__global__ __launch_bounds__(256) void pad_k(const float* __restrict__ bqkv,
                                             float* __restrict__ kb, float* __restrict__ vb)
{
    int i = blockIdx.x * 256 + threadIdx.x;   // over BQ*GQ*256 = 8192 rows
    if (i >= BQ * GQ * 256) return;
    int c = i & 255;
    int g = (i >> 8) & (GQ - 1);
    kb[(size_t)i * SKQ + SQ] = bqkv[g * 768 + c * 3 + 1];
    vb[(size_t)i * SKQ + SQ] = bqkv[g * 768 + c * 3 + 2];
}

// ---------------------------------------------------------------------------
// Attention: block = (t-tile of 16, head n, batch b), 256 threads.
// scores[g][e] = (1/sqrt(32)) * sum_d q[g,n,d,t] * k[e,n,d,t(+1 if e>=8)]
// z = sigmoid(scores); attn = z / (1e-9 + sum_e z)
// og[g,n,d,t] = sum_e attn[g][e] * v[e,n,d,t(+1)]
// og overwrites the q buffer in-place (same rows, read-before-write).
// ---------------------------------------------------------------------------
__global__ __launch_bounds__(256) void attn_k(
    const float* q,                    // aliases og -> no __restrict__
    const float* __restrict__ k, const float* __restrict__ v,
    float* og,                         // aliases q
    float* __restrict__ aout)
{
    __shared__ float qo_s[4620];   // q: [(d*8+g)*18 + t] ; later og: [(g*32+d)*18 + 2g + t]
    __shared__ float k_s[4607];    // [(d*8+e8)*18 + t(+hi)]
    __shared__ float v_s[4607];    // [(e8*32+d)*18 + t(+hi)]
    __shared__ float at_s[2182];   // [(g*16+e)*17 + g + t]

    const int tid = threadIdx.x;
    const int t0 = blockIdx.x << 4;
    const int n  = blockIdx.y;
    const int b  = blockIdx.z;

    // ---- stage q (256 rows x 16 cols) ----
#pragma unroll
    for (int i = 0; i < 4; ++i) {
        int f = tid + (i << 8);                 // 0..1023
        int row = f >> 2, cq = f & 3;           // row = d*8+g
        int d = row >> 3, g = row & 7;
        const float4 val = *(const float4*)(q + ((size_t)((b * GQ + g) * 256 + n * 32 + d)) * SQ + t0 + (cq << 2));
        float* lp = &qo_s[row * 18 + (cq << 2)];
        lp[0] = val.x; lp[1] = val.y; lp[2] = val.z; lp[3] = val.w;
    }
    // ---- stage k,v (256 rows x 17 cols; col 16 is t0+16, for the +1 shift) ----
#pragma unroll
    for (int i = 0; i < 4; ++i) {
        int f = tid + (i << 8);
        int r = f >> 2, cq = f & 3;
        int d = r >> 3, e8 = r & 7;
        size_t gofs = ((size_t)((b * GQ + e8) * 256 + n * 32 + d)) * SKQ + t0 + (cq << 2);
        const float4 k4 = *(const float4*)(k + gofs);
        float* lk = &k_s[(d * 8 + e8) * 18 + (cq << 2)];
        lk[0] = k4.x; lk[1] = k4.y; lk[2] = k4.z; lk[3] = k4.w;
        const float4 v4 = *(const float4*)(v + gofs);
        float* lv = &v_s[(e8 * 32 + d) * 18 + (cq << 2)];
        lv[0] = v4.x; lv[1] = v4.y; lv[2] = v4.z; lv[3] = v4.w;
    }
    {   // tail column (index 16)
        int r = tid;
        if (r < 256) {
            int d = r >> 3, e8 = r & 7;
            size_t gofs = ((size_t)((b * GQ + e8) * 256 + n * 32 + d)) * SKQ + t0 + 16;
            k_s[(d * 8 + e8) * 18 + 16] = k[gofs];
            v_s[(e8 * 32 + d) * 18 + 16] = v[gofs];
        }
    }
    __syncthreads();

    // ---- scores + sigmoid-normalize: lanes = (g, e), 2 t per pass ----
    {
        const int p = tid >> 7;                 // t parity
        const int idx = tid & 127;
        const int g = idx >> 4, e = idx & 15;
        const int e8 = e & 7, hi = e >> 3;
#pragma unroll
        for (int it = 0; it < 8; ++it) {
            const int t = (it << 1) + p;
            float s = 0.f;
#pragma unroll
            for (int d = 0; d < 32; ++d)
                s += qo_s[(d * 8 + g) * 18 + t] * k_s[(d * 8 + e8) * 18 + t + hi];
            s *= 0.17677669529663687f;          // 1/sqrt(32)
            const float z = 1.f / (1.f + expf(-s));
            float zs = z;
#pragma unroll
            for (int off = 1; off < 16; off <<= 1)
                zs += __shfl_xor(zs, off);
            at_s[(g * 16 + e) * 17 + g + t] = z / (1e-9f + zs);
        }
    }
    __syncthreads();

    // ---- PV: lanes = (g, dq), 4 t per pass; writes og into qo_s ----
    {
        const int p4 = tid >> 6;
        const int l = tid & 63;
        const int g = l >> 3, dq = l & 7;
#pragma unroll
        for (int it = 0; it < 4; ++it) {
            const int t = (it << 2) + p4;
            float a0 = 0.f, a1 = 0.f, a2 = 0.f, a3 = 0.f;
#pragma unroll
            for (int e = 0; e < 16; ++e) {
                const int e8 = e & 7, hi = e >> 3;
                const float a = at_s[(g * 16 + e) * 17 + g + t];
                const float* vp = &v_s[(e8 * 32 + (dq << 2)) * 18 + t + hi];
                a0 += a * vp[0 * 18];
                a1 += a * vp[1 * 18];
                a2 += a * vp[2 * 18];
                a3 += a * vp[3 * 18];
            }
            float* op = &qo_s[((g << 5) + (dq << 2)) * 18 + (g << 1) + t];
            op[0 * 18] = a0; op[1 * 18] = a1; op[2 * 18] = a2; op[3 * 18] = a3;
        }
    }
    __syncthreads();

    // ---- store attn_out (128 rows x 16), coalesced float2 ----
#pragma unroll
    for (int i = 0; i < 4; ++i) {
        int f = tid + (i << 8);                 // 0..1023
        int row = f >> 3, t2 = f & 7;           // row = g*16+e
        int gg = row >> 4;
        float x0 = at_s[row * 17 + gg + (t2 << 1)];
        float x1 = at_s[row * 17 + gg + (t2 << 1) + 1];
        float* gp = aout + ((size_t)((b * NHQ + n) * 128 + row)) * SQ + t0 + (t2 << 1);
        *(float2*)gp = make_float2(x0, x1);
    }
    // ---- store og (256 rows x 16), coalesced float2 ----
#pragma unroll
    for (int i = 0; i < 8; ++i) {
        int f = tid + (i << 8);                 // 0..2047
        int row = f >> 3, t2 = f & 7;           // row = g*32+d
        int gg = row >> 5, d = row & 31;
        float x0 = qo_s[row * 18 + (gg << 1) + (t2 << 1)];
        float x1 = qo_s[row * 18 + (gg << 1) + (t2 << 1) + 1];
        float* gp = og + ((size_t)((b * GQ + gg) * 256 + n * 32 + d)) * SQ + t0 + (t2 << 1);
        *(float2*)gp = make_float2(x0, x1);
    }
}

// ---------------------------------------------------------------------------
extern "C" void kernel_launch(void* const* d_in, const int* in_sizes, int n_in,
                              void* d_out, int out_size, void* d_ws, size_t ws_size,
                              hipStream_t stream)
{
    const float* x      = (const float*)d_in[0];
    const float* w_qkv  = (const float*)d_in[1];
    const float* b_qkv  = (const float*)d_in[2];
    const float* w_pred = (const float*)d_in[3];
    const float* b_pred = (const float*)d_in[4];

    float* pred = (float*)d_out;                                  // (B, 2048, S)
    float* aout = (float*)d_out + (size_t)BQ * 2048 * SQ;         // (B, NH, G, 2G, S)

    float* qog = (float*)d_ws;                                    // q, then og (in-place)
    float* kb  = qog + (size_t)BQ * GQ * 256 * SQ;
    float* vb  = kb + (size_t)BQ * GQ * 256 * SKQ;

    // 1) QKV projection GEMM -> q/k/v (t-major rows)
    gemm_k<768, true><<<dim3(32, 6, BQ * GQ), 256, 0, stream>>>(w_qkv, x, b_qkv, qog, kb, vb);
    // 2) pad column t=S of k/v (bias only)
    pad_k<<<32, 256, 0, stream>>>(b_qkv, kb, vb);
    // 3) attention (og overwrites q in-place)
    attn_k<<<dim3(SQ / 16, NHQ, BQ), 256, 0, stream>>>(qog, kb, vb, qog, aout);
    // 4) pred projection GEMM
    gemm_k<256, false><<<dim3(32, 2, BQ * GQ), 256, 0, stream>>>(w_pred, qog, b_pred, pred, nullptr, nullptr);
}

// Round 2
// 860.632 us; speedup vs baseline: 1.3912x; 1.3912x over previous
//
#include <hip/hip_runtime.h>
#include <math.h>

// Problem constants
#define BQ   4
#define GQ   8
#define NHQ  8
#define SQ   4096

// ---------------------------------------------------------------------------
// Memory plan (NOTE: requires ws_size >= 512 MiB exactly = 536,870,912 B):
//   d_ws: q      fp32 [bg][c][t]      134,217,728 B
//         kb     fp32 [bg][c][t]      134,217,728 B
//         vb     fp32 [bg][c][t]      134,217,728 B
//         og_hi  bf16 [bg][t][c]       67,108,864 B
//         og_lo  bf16 [bg][t][c]       67,108,864 B
//   d_out pred region (free until final GEMM): xt_hi/xt_lo bf16 [bg][t][c]
//         (exactly fills it); later first 64 KiB reused for k/v pad columns.
//   d_out attn region: written only by attn_k (aout).
// Kernel order (one stream, serialized): convert_x -> qkv gemm -> pad ->
//   attn -> pred gemm.
// ---------------------------------------------------------------------------

typedef __attribute__((ext_vector_type(8))) short short8;
typedef __attribute__((ext_vector_type(4))) float f32x4;

__device__ __forceinline__ unsigned short f2b(float f) {
    unsigned int u = __float_as_uint(f);
    unsigned int r = u + 0x7fffu + ((u >> 16) & 1u);   // RNE
    return (unsigned short)(r >> 16);
}
__device__ __forceinline__ float b2f(unsigned short h) {
    return __uint_as_float(((unsigned int)h) << 16);
}
__device__ __forceinline__ void gll16(const void* g, void* l) {
    __builtin_amdgcn_global_load_lds((const __attribute__((address_space(1))) void*)g,
                                     (__attribute__((address_space(3))) void*)l, 16, 0, 0);
}

// ---------------------------------------------------------------------------
// Transpose+convert: x fp32 [bg][c][t] -> xt_hi/xt_lo bf16 [bg][t][c]
// ---------------------------------------------------------------------------
__global__ __launch_bounds__(256) void convert_x_k(const float* __restrict__ x,
    unsigned short* __restrict__ xhi, unsigned short* __restrict__ xlo)
{
    __shared__ float lds[64 * 65];
    const int tid = threadIdx.x;
    const int t0 = blockIdx.x << 6;
    const int c0 = blockIdx.y << 6;
    const int bg = blockIdx.z;
    const int hi16 = tid >> 4, lo16 = tid & 15;
    const float* xb = x + ((size_t)bg << 8) * SQ;
#pragma unroll
    for (int p = 0; p < 4; ++p) {
        int c = (p << 4) + hi16;
        const float4 v4 = *(const float4*)(xb + (size_t)(c0 + c) * SQ + t0 + (lo16 << 2));
        lds[((lo16 << 2) + 0) * 65 + c] = v4.x;
        lds[((lo16 << 2) + 1) * 65 + c] = v4.y;
        lds[((lo16 << 2) + 2) * 65 + c] = v4.z;
        lds[((lo16 << 2) + 3) * 65 + c] = v4.w;
    }
    __syncthreads();
#pragma unroll
    for (int p = 0; p < 4; ++p) {
        int t = (p << 4) + hi16;
        float f0 = lds[t * 65 + (lo16 << 2) + 0];
        float f1 = lds[t * 65 + (lo16 << 2) + 1];
        float f2 = lds[t * 65 + (lo16 << 2) + 2];
        float f3 = lds[t * 65 + (lo16 << 2) + 3];
        ushort4 h, l;
        h.x = f2b(f0); l.x = f2b(f0 - b2f(h.x));
        h.y = f2b(f1); l.y = f2b(f1 - b2f(h.y));
        h.z = f2b(f2); l.z = f2b(f2 - b2f(h.z));
        h.w = f2b(f3); l.w = f2b(f3 - b2f(h.w));
        size_t o = (((size_t)bg * SQ + t0 + t) << 8) + c0 + (lo16 << 2);
        *(ushort4*)(xhi + o) = h;
        *(ushort4*)(xlo + o) = l;
    }
}

// ---------------------------------------------------------------------------
// Split-bf16 MFMA GEMM: C[o][t] = sum_c W[g][o][c] * B[bg][t][c] + bias
// 128x128 tile, BK=32, 4 waves, 16x16x32 bf16 MFMA, 3 products (hh, hl, lh).
// B planes: global_load_lds(16B) with inverse-swizzled source; A: fp32
// reg-stage + convert + swizzled ds_write.
// LDS chunk swizzle: phys16Bchunk = chunk ^ ((row>>1)&3)  (2 lanes/bank max).
// ---------------------------------------------------------------------------
template <int M, bool QKV>
__global__ __launch_bounds__(256) void gemm2_k(
    const float* __restrict__ W,
    const unsigned short* __restrict__ Bh, const unsigned short* __restrict__ Bl,
    const float* __restrict__ bias,
    float* __restrict__ o0p, float* __restrict__ o1p, float* __restrict__ o2p)
{
    __shared__ __align__(16) char smem[32768];
    const int AHI = 0, ALO = 8192, BHI = 16384, BLO = 24576;
    const int tid = threadIdx.x;
    const int lane = tid & 63, wid = tid >> 6;
    const int wm = wid >> 1, wn = wid & 1;
    const int o0 = blockIdx.x << 7;
    const int t0 = blockIdx.y << 7;
    const int bg = blockIdx.z;
    const int g = bg & 7;
    const float* Wg = W + (size_t)g * M * 256;
    const size_t brow0 = (((size_t)bg * SQ + t0) << 8);

    f32x4 acc[4][4];
    const f32x4 zero = {0.f, 0.f, 0.f, 0.f};
#pragma unroll
    for (int i = 0; i < 4; ++i)
#pragma unroll
        for (int j = 0; j < 4; ++j) acc[i][j] = zero;

    for (int k0 = 0; k0 < 256; k0 += 32) {
        // ---- B tiles (hi/lo) via async global->LDS, inverse-swizzled source
#pragma unroll
        for (int s = 0; s < 2; ++s) {
            int w = tid + (s << 8);                 // 0..511 16B chunks
            int row = w >> 2;
            int j = (w & 3) ^ ((w >> 3) & 3);       // (w>>3)&3 == (row>>1)&3
            size_t go = brow0 + ((size_t)row << 8) + k0 + (j << 3);
            gll16(Bh + go, smem + BHI + (w << 4));
            gll16(Bl + go, smem + BLO + (w << 4));
        }
        // ---- A tile: fp32 load, split, swizzled ds_write
#pragma unroll
        for (int p = 0; p < 4; ++p) {
            int qd = tid + (p << 8);                // 0..1023 float4 chunks
            int row = qd >> 3, kq = qd & 7;
            const float4 a4 = *(const float4*)(Wg + (size_t)(o0 + row) * 256 + k0 + (kq << 2));
            ushort4 h, l;
            h.x = f2b(a4.x); l.x = f2b(a4.x - b2f(h.x));
            h.y = f2b(a4.y); l.y = f2b(a4.y - b2f(h.y));
            h.z = f2b(a4.z); l.z = f2b(a4.z - b2f(h.z));
            h.w = f2b(a4.w); l.w = f2b(a4.w - b2f(h.w));
            int base = (row << 6) + ((((kq >> 1) ^ ((row >> 1) & 3)) << 4)) + ((kq & 1) << 3);
            *(ushort4*)(smem + AHI + base) = h;
            *(ushort4*)(smem + ALO + base) = l;
        }
        __syncthreads();

        short8 ah[4], al[4], bh[4], bl[4];
        const int lr = lane & 15, kc = lane >> 4;
#pragma unroll
        for (int mi = 0; mi < 4; ++mi) {
            int row = (wm << 6) + (mi << 4) + lr;
            int off = (row << 6) + ((kc ^ ((row >> 1) & 3)) << 4);
            ah[mi] = *(const short8*)(smem + AHI + off);
            al[mi] = *(const short8*)(smem + ALO + off);
        }
#pragma unroll
        for (int ni = 0; ni < 4; ++ni) {
            int row = (wn << 6) + (ni << 4) + lr;
            int off = (row << 6) + ((kc ^ ((row >> 1) & 3)) << 4);
            bh[ni] = *(const short8*)(smem + BHI + off);
            bl[ni] = *(const short8*)(smem + BLO + off);
        }
#pragma unroll
        for (int mi = 0; mi < 4; ++mi)
#pragma unroll
            for (int ni = 0; ni < 4; ++ni)
                acc[mi][ni] = __builtin_amdgcn_mfma_f32_16x16x32_bf16(ah[mi], bh[ni], acc[mi][ni], 0, 0, 0);
#pragma unroll
        for (int mi = 0; mi < 4; ++mi)
#pragma unroll
            for (int ni = 0; ni < 4; ++ni)
                acc[mi][ni] = __builtin_amdgcn_mfma_f32_16x16x32_bf16(ah[mi], bl[ni], acc[mi][ni], 0, 0, 0);
#pragma unroll
        for (int mi = 0; mi < 4; ++mi)
#pragma unroll
            for (int ni = 0; ni < 4; ++ni)
                acc[mi][ni] = __builtin_amdgcn_mfma_f32_16x16x32_bf16(al[mi], bh[ni], acc[mi][ni], 0, 0, 0);
        __syncthreads();
    }

    // ---- epilogue: C layout col=lane&15 (t), row=(lane>>4)*4+r (o)
    const int lr = lane & 15, lq = lane >> 4;
#pragma unroll
    for (int mi = 0; mi < 4; ++mi) {
#pragma unroll
        for (int r = 0; r < 4; ++r) {
            const int row = o0 + (wm << 6) + (mi << 4) + (lq << 2) + r;
            const float bo = bias[g * M + row];
            float* rowbase;
            if (QKV) {
                const int j = row % 3, c = row / 3;
                float* bp = (j == 0) ? o0p : ((j == 1) ? o1p : o2p);
                rowbase = bp + (((size_t)bg * 256 + c) << 12);
            } else {
                rowbase = o0p + (((size_t)(bg >> 3) * 2048 + g * 256 + row) << 12);
            }
#pragma unroll
            for (int ni = 0; ni < 4; ++ni) {
                const int t = t0 + (wn << 6) + (ni << 4) + lr;
                rowbase[t] = acc[mi][ni][r] + bo;
            }
        }
    }
}

// ---------------------------------------------------------------------------
// k/v pad column (t = S): x pad column is zero -> value = bias only.
// ---------------------------------------------------------------------------
__global__ __launch_bounds__(256) void pad_k(const float* __restrict__ bqkv,
                                             float* __restrict__ kpad, float* __restrict__ vpad)
{
    int i = blockIdx.x * 256 + threadIdx.x;    // BQ*GQ*256 = 8192
    int c = i & 255;
    int g = (i >> 8) & 7;
    kpad[i] = bqkv[g * 768 + c * 3 + 1];
    vpad[i] = bqkv[g * 768 + c * 3 + 2];
}

// ---------------------------------------------------------------------------
// Attention (unchanged math from verified round-1): block=(t-tile 16, n, b).
// og now written as bf16 hi/lo planes in [bg][t][c] layout for pred GEMM.
// ---------------------------------------------------------------------------
__global__ __launch_bounds__(256) void attn_k(
    const float* __restrict__ q, const float* __restrict__ k, const float* __restrict__ v,
    const float* __restrict__ kpad, const float* __restrict__ vpad,
    unsigned short* __restrict__ oghi, unsigned short* __restrict__ oglo,
    float* __restrict__ aout)
{
    __shared__ float qo_s[4620];
    __shared__ float k_s[4607];
    __shared__ float v_s[4607];
    __shared__ float at_s[2182];

    const int tid = threadIdx.x;
    const int t0 = blockIdx.x << 4;
    const int n  = blockIdx.y;
    const int b  = blockIdx.z;

    // ---- stage q ----
#pragma unroll
    for (int i = 0; i < 4; ++i) {
        int f = tid + (i << 8);
        int row = f >> 2, cq = f & 3;
        int d = row >> 3, g = row & 7;
        const float4 val = *(const float4*)(q + (((size_t)((b * GQ + g) * 256 + n * 32 + d)) << 12) + t0 + (cq << 2));
        float* lp = &qo_s[row * 18 + (cq << 2)];
        lp[0] = val.x; lp[1] = val.y; lp[2] = val.z; lp[3] = val.w;
    }
    // ---- stage k,v (cols 0..15 = t, col 16 = t0+16 for the +1 shift) ----
#pragma unroll
    for (int i = 0; i < 4; ++i) {
        int f = tid + (i << 8);
        int r = f >> 2, cq = f & 3;
        int d = r >> 3, e8 = r & 7;
        size_t gofs = (((size_t)((b * GQ + e8) * 256 + n * 32 + d)) << 12) + t0 + (cq << 2);
        const float4 k4 = *(const float4*)(k + gofs);
        float* lk = &k_s[(d * 8 + e8) * 18 + (cq << 2)];
        lk[0] = k4.x; lk[1] = k4.y; lk[2] = k4.z; lk[3] = k4.w;
        const float4 v4 = *(const float4*)(v + gofs);
        float* lv = &v_s[(e8 * 32 + d) * 18 + (cq << 2)];
        lv[0] = v4.x; lv[1] = v4.y; lv[2] = v4.z; lv[3] = v4.w;
    }
    {   // tail column (index 16)
        int r = tid;
        int d = r >> 3, e8 = r & 7;
        float kv, vv;
        if (t0 + 16 < SQ) {
            size_t gofs = (((size_t)((b * GQ + e8) * 256 + n * 32 + d)) << 12) + t0 + 16;
            kv = k[gofs]; vv = v[gofs];
        } else {
            int pi = (b * GQ + e8) * 256 + n * 32 + d;
            kv = kpad[pi]; vv = vpad[pi];
        }
        k_s[(d * 8 + e8) * 18 + 16] = kv;
        v_s[(e8 * 32 + d) * 18 + 16] = vv;
    }
    __syncthreads();

    // ---- scores + sigmoid-normalize ----
    {
        const int p = tid >> 7;
        const int idx = tid & 127;
        const int g = idx >> 4, e = idx & 15;
        const int e8 = e & 7, hi = e >> 3;
#pragma unroll
        for (int it = 0; it < 8; ++it) {
            const int t = (it << 1) + p;
            float s = 0.f;
#pragma unroll
            for (int d = 0; d < 32; ++d)
                s += qo_s[(d * 8 + g) * 18 + t] * k_s[(d * 8 + e8) * 18 + t + hi];
            s *= 0.17677669529663687f;
            const float z = 1.f / (1.f + __expf(-s));
            float zs = z;
#pragma unroll
            for (int off = 1; off < 16; off <<= 1)
                zs += __shfl_xor(zs, off);
            at_s[(g * 16 + e) * 17 + g + t] = z / (1e-9f + zs);
        }
    }
    __syncthreads();

    // ---- PV: og into qo_s ----
    {
        const int p4 = tid >> 6;
        const int l = tid & 63;
        const int g = l >> 3, dq = l & 7;
#pragma unroll
        for (int it = 0; it < 4; ++it) {
            const int t = (it << 2) + p4;
            float a0 = 0.f, a1 = 0.f, a2 = 0.f, a3 = 0.f;
#pragma unroll
            for (int e = 0; e < 16; ++e) {
                const int e8 = e & 7, hi = e >> 3;
                const float a = at_s[(g * 16 + e) * 17 + g + t];
                const float* vp = &v_s[(e8 * 32 + (dq << 2)) * 18 + t + hi];
                a0 += a * vp[0 * 18];
                a1 += a * vp[1 * 18];
                a2 += a * vp[2 * 18];
                a3 += a * vp[3 * 18];
            }
            float* op = &qo_s[((g << 5) + (dq << 2)) * 18 + (g << 1) + t];
            op[0 * 18] = a0; op[1 * 18] = a1; op[2 * 18] = a2; op[3 * 18] = a3;
        }
    }
    __syncthreads();

    // ---- store attn_out ----
#pragma unroll
    for (int i = 0; i < 4; ++i) {
        int f = tid + (i << 8);
        int row = f >> 3, t2 = f & 7;
        int gg = row >> 4;
        float x0 = at_s[row * 17 + gg + (t2 << 1)];
        float x1 = at_s[row * 17 + gg + (t2 << 1) + 1];
        float* gp = aout + (((size_t)((b * NHQ + n) * 128 + row)) << 12) + t0 + (t2 << 1);
        *(float2*)gp = make_float2(x0, x1);
    }
    // ---- store og as bf16 hi/lo, [bg][t][c] with c = n*32+d ----
#pragma unroll
    for (int i = 0; i < 16; ++i) {
        int f = tid + (i << 8);                 // 0..4095
        int t = f >> 8, rc = f & 255;           // rc = g*32+d
        int gg = rc >> 5, d = rc & 31;
        float val = qo_s[rc * 18 + (gg << 1) + t];
        unsigned short hh = f2b(val);
        unsigned short ll = f2b(val - b2f(hh));
        size_t o = (((size_t)((b * GQ + gg) * SQ + t0 + t)) << 8) + n * 32 + d;
        oghi[o] = hh;
        oglo[o] = ll;
    }
}

// ---------------------------------------------------------------------------
extern "C" void kernel_launch(void* const* d_in, const int* in_sizes, int n_in,
                              void* d_out, int out_size, void* d_ws, size_t ws_size,
                              hipStream_t stream)
{
    const float* x      = (const float*)d_in[0];
    const float* w_qkv  = (const float*)d_in[1];
    const float* b_qkv  = (const float*)d_in[2];
    const float* w_pred = (const float*)d_in[3];
    const float* b_pred = (const float*)d_in[4];

    float* pred = (float*)d_out;                             // 33,554,432 f
    float* aout = pred + (size_t)33554432;                   // 16,777,216 f

    unsigned short* xt_hi = (unsigned short*)d_out;          // scratch in pred region
    unsigned short* xt_lo = xt_hi + (size_t)33554432;
    float* kpad = (float*)d_out;                             // reused after qkv gemm
    float* vpad = kpad + 8192;

    float* q  = (float*)d_ws;
    float* kb = q + (size_t)33554432;
    float* vb = kb + (size_t)33554432;
    unsigned short* og_hi = (unsigned short*)(vb + (size_t)33554432);
    unsigned short* og_lo = og_hi + (size_t)33554432;

    // 1) x -> bf16 hi/lo transposed [bg][t][c]
    convert_x_k<<<dim3(64, 4, 32), 256, 0, stream>>>(x, xt_hi, xt_lo);
    // 2) QKV projection (split-bf16 MFMA) -> q/k/v fp32 [bg][c][t]
    gemm2_k<768, true><<<dim3(6, 32, 32), 256, 0, stream>>>(w_qkv, xt_hi, xt_lo, b_qkv, q, kb, vb);
    // 3) pad columns (bias only) -- after qkv gemm (overwrites xt head)
    pad_k<<<32, 256, 0, stream>>>(b_qkv, kpad, vpad);
    // 4) attention -> aout + og hi/lo [bg][t][c]
    attn_k<<<dim3(SQ / 16, NHQ, BQ), 256, 0, stream>>>(q, kb, vb, kpad, vpad, og_hi, og_lo, aout);
    // 5) pred projection (split-bf16 MFMA) -> pred
    gemm2_k<256, false><<<dim3(2, 32, 32), 256, 0, stream>>>(w_pred, og_hi, og_lo, b_pred, pred, nullptr, nullptr);
}